// Round 12
// baseline (532.890 us; speedup 1.0000x reference)
//
#include <hip/hip_runtime.h>
#include <hip/hip_bf16.h>
#include <hip/hip_fp16.h>
#include <math.h>

typedef _Float16 f16x8 __attribute__((ext_vector_type(8)));
typedef _Float16 h2 __attribute__((ext_vector_type(2)));
typedef __fp16 h2amd __attribute__((ext_vector_type(2)));   // builtin return type
typedef float f32x16 __attribute__((ext_vector_type(16)));
typedef float f32x2 __attribute__((ext_vector_type(2)));

#define DH 100      // hidden dim
#define SPB 20      // samples per block -> 2020 rows, padded to 2048
#define NIT 8       // iterations; each processes 2 chunks of 128 rows

// ws float offsets
#define WS_CCW   0
#define WS_XSC   128
#define WS_OH0   256
#define WS_EOH1  260
#define WS_X2    272
#define WS_WF    16704   // f16 weight-fragment region (byte offset 66816, 16B-aligned)
// fragment-major f16 layout: per (arr,k): [group=nt*7+ks][lane 0..63][j 0..7]
//   W1frag[k] at half-offset k*14336 ; W2frag[k] at 43008 + k*14336
#define FRAG_PER_K 14336
#define W2_BASE    43008
#define FRAG_TOTAL 86016

__device__ __forceinline__ unsigned short f2bf(float f) {
    unsigned int u = __float_as_uint(f);
    unsigned int r = (u + 0x7FFFu + ((u >> 16) & 1u)) >> 16;  // RNE
    return (unsigned short)r;
}
__device__ __forceinline__ unsigned int hpk(float a, float b) {
    union { h2amd h; unsigned int u; } c;
    c.h = __builtin_amdgcn_cvt_pkrtz(a, b);
    return c.u;
}
__device__ __forceinline__ h2 hpk2(float a, float b) {
    union { h2amd ha; h2 h; } c;
    c.ha = __builtin_amdgcn_cvt_pkrtz(a, b);
    return c.h;
}

__global__ void setup_kernel(const float* __restrict__ logits,
                             const float* __restrict__ iW1, const float* __restrict__ ib1,
                             const float* __restrict__ iW2, const float* __restrict__ ib2,
                             const float* __restrict__ hb0,
                             const float* __restrict__ hW1,
                             const float* __restrict__ hb1,
                             const float* __restrict__ hW2,
                             const float* __restrict__ hb2,
                             const float* __restrict__ hW3,
                             const float* __restrict__ hb3,
                             float* __restrict__ ws,
                             float* __restrict__ out2, int n)
{
    int t = threadIdx.x;
    for (int i = blockIdx.x * blockDim.x + t; i < n; i += gridDim.x * blockDim.x)
        out2[i] = logits[i];

    // f16 weight fragments, fragment-major (coalesced 1KB wave loads in mono)
    _Float16* wsH = (_Float16*)(ws + WS_WF);
    for (int i = blockIdx.x * blockDim.x + t; i < FRAG_TOTAL; i += gridDim.x * blockDim.x) {
        int arr = i / W2_BASE;                 // 0 = W1, 1 = W2
        int rem = i - arr * W2_BASE;
        int k = rem / FRAG_PER_K;
        int r2 = rem - k * FRAG_PER_K;
        int group = r2 >> 9;                   // nt*7 + ks, 0..27
        int lane = (r2 >> 3) & 63;
        int j = r2 & 7;
        int nt = group / 7, ks = group - nt * 7;
        int row = nt * 32 + (lane & 31);
        if (row > DH - 1) row = DH - 1;        // clamp (garbage killed downstream)
        int col = ks * 16 + (lane >> 5) * 8 + j;
        const float* Wg = arr ? iW2 : iW1;
        const float* bg = arr ? ib2 : ib1;
        float v;
        if (col < DH)       v = Wg[(k * DH + row) * DH + col];
        else if (col == DH) v = bg[k * DH + row];
        else                v = 0.f;
        wsH[i] = (_Float16)v;
    }
    if (blockIdx.x != 0) return;

    if (t < 128) {
        double ccw = 0.0, xs = 0.0;
        if (t <= 100) {
            double s = (double)t;
            for (int j = 0; j <= 100; j += 2) {
                double wj = (j == 0) ? 1.0 : 2.0 / (1.0 - (double)j * (double)j);
                double lam;
                if (t == 0) lam = 0.5;
                else {
                    lam = cos((double)j * s * M_PI / 100.0);
                    if (t == 100) lam *= 0.5;
                }
                ccw += lam * 0.02 * wj;
            }
            xs = (cos(s * M_PI / 100.0) + 1.0) * 0.5;
        }
        ws[WS_CCW + t] = (float)ccw;
        ws[WS_XSC + t] = (float)xs;
    }
    __syncthreads();

    __shared__ float bufA[DH], bufB[DH];
    for (int k = 0; k < 3; ++k) {
        if (t < DH) bufA[t] = fmaxf(hb0[k * DH + t], 0.f);
        __syncthreads();
        if (t < DH) {
            float acc = hb1[k * DH + t];
            const float* w = hW1 + (size_t)(k * DH + t) * DH;
            for (int i = 0; i < DH; ++i) acc = fmaf(w[i], bufA[i], acc);
            bufB[t] = fmaxf(acc, 0.f);
        }
        __syncthreads();
        if (t < DH) {
            float acc = hb2[k * DH + t];
            const float* w = hW2 + (size_t)(k * DH + t) * DH;
            for (int i = 0; i < DH; ++i) acc = fmaf(w[i], bufB[i], acc);
            bufA[t] = fmaxf(acc, 0.f);
        }
        __syncthreads();
        if (t < 2) {
            float acc = hb3[k * 2 + t];
            const float* w = hW3 + (size_t)(k * 2 + t) * DH;
            for (int i = 0; i < DH; ++i) acc = fmaf(w[i], bufA[i], acc);
            if (t == 0) ws[WS_OH0 + k] = acc;
            else        ws[WS_EOH1 + k] = expf(acc);
        }
        __syncthreads();
    }
}

// Transposed dataflow (verified R3-R11): C1 = W1·A1^T, C2 = W2·A2^T; C->B
// transform via lane^32 shuffle exchange; all hot-loop loads laundered
// through an opaque zero offset (blocks LICM register caching = R4/R5 spill).
// R12: weight matrices evicted from LDS -> L2 (fragment-major f16 in ws,
// 1KB coalesced wave loads). Block LDS ~2.3 KB -> occupancy VGPR-capped at
// ~16 waves/CU instead of LDS-capped 3 blocks (the R7-R11 latency wall).
__global__ __launch_bounds__(256)
void mono_mfma(const float* __restrict__ xsrc,
               const float* __restrict__ iW0, const float* __restrict__ ib0,
               const float* __restrict__ iW3, const float* __restrict__ ib3,
               const float* __restrict__ ws,
               float* __restrict__ dst0, float* __restrict__ dst1,
               int kbase, int nTot)
{
    __shared__ unsigned int w0p_s[64];    // f16 pairs of w0: pair j = slots {2j,2j+1}; 0 past DH
    __shared__ unsigned int b0p_s[64];    // f16 pairs of b0; slot 100 = 1.0
    __shared__ unsigned int w3p_s[64];    // packed bf16 w3 pairs, [hf][nt2][q][pr]; 0 for n2>=100
    __shared__ float xsc_s[128], ccw_s[128];
    __shared__ float xs_s[32], zs[32];

    const int tid = threadIdx.x;
    const int lane = tid & 63;
    const int wv = tid >> 6;
    const int hf = lane >> 5;
    const bool hfb = (hf != 0);
    const int l31 = lane & 31;
    const int k = kbase + blockIdx.y;
    float* __restrict__ dst = (blockIdx.y == 0) ? dst0 : dst1;

    const _Float16* __restrict__ W1f = (const _Float16*)(ws + WS_WF) + k * FRAG_PER_K + lane * 8;
    const _Float16* __restrict__ W2f = (const _Float16*)(ws + WS_WF) + W2_BASE + k * FRAG_PER_K + lane * 8;

    if (tid < 128) {
        xsc_s[tid] = ws[WS_XSC + tid];
        ccw_s[tid] = ws[WS_CCW + tid];
    }
    if (tid < 64) {
        int s0 = 2 * tid, s1 = 2 * tid + 1;
        float w0a = (s0 < DH) ? iW0[(k * DH + s0) * 3] : 0.f;   // h==0: feature 0 only
        float w0b = (s1 < DH) ? iW0[(k * DH + s1) * 3] : 0.f;
        float b0a = (s0 < DH) ? ib0[k * DH + s0] : ((s0 == DH) ? 1.f : 0.f);
        float b0b = (s1 < DH) ? ib0[k * DH + s1] : 0.f;
        w0p_s[tid] = hpk(w0a, w0b);
        b0p_s[tid] = hpk(b0a, b0b);

        int hf_i = tid >> 5, rem = tid & 31;
        int nt2 = rem >> 3, qq = (rem >> 1) & 3, pr = rem & 1;
        int n2e = 32 * nt2 + 8 * qq + 2 * pr + 4 * hf_i;
        float we = (n2e < DH) ? iW3[k * DH + n2e] : 0.f;
        float wo = (n2e + 1 < DH) ? iW3[k * DH + n2e + 1] : 0.f;
        w3p_s[tid] = ((unsigned int)f2bf(wo) << 16) | (unsigned int)f2bf(we);
    }
    if (tid < 32) {
        int n = blockIdx.x * SPB + tid;
        xs_s[tid] = (tid < SPB && n < nTot) ? xsrc[n] : 0.f;
        zs[tid] = 0.f;
    }
    __syncthreads();

    const float b3 = ib3[k];
    const float e1 = ws[WS_EOH1 + k];
    const float o0 = ws[WS_OH0 + k];

    union FR { f16x8 v; h2 h[4]; unsigned int u32[4]; };
    const f32x2 zero2 = {0.f, 0.f};

    #pragma unroll 1
    for (int it = 0; it < NIT; ++it) {
        // Opaque zero: every weight/const load below depends on it -> LICM blocked.
        unsigned int zoff = 0;
        asm volatile("" : "+v"(zoff));

        int nloc[2], p[2];
        h2 uu[2];
        #pragma unroll
        for (int j = 0; j < 2; ++j) {
            int mrow = it * 256 + j * 128 + wv * 32 + l31;
            nloc[j] = (mrow * 649) >> 16;   // mrow / 101 (exact for mrow < 2048)
            p[j] = mrow - nloc[j] * 101;
            float u = xs_s[nloc[j]] * xsc_s[p[j]];
            uu[j] = hpk2(u, u);
        }

        // ---- layer 1: B-frags for BOTH chunks, sharing w0/b0 loads ----
        FR a1[2][7];
        #pragma unroll
        for (int ks = 0; ks < 7; ++ks) {
            int pb = ks * 8 + hf * 4 + zoff;          // pair base
            uint4 wq = *(const uint4*)&w0p_s[pb];
            uint4 bq = *(const uint4*)&b0p_s[pb];
            unsigned int wqa[4] = {wq.x, wq.y, wq.z, wq.w};
            unsigned int bqa[4] = {bq.x, bq.y, bq.z, bq.w};
            #pragma unroll
            for (int i = 0; i < 4; ++i) {
                union { unsigned int u; h2 h; } cw, cb;
                cw.u = wqa[i]; cb.u = bqa[i];
                h2 z = {(_Float16)0.f, (_Float16)0.f};
                #pragma unroll
                for (int j = 0; j < 2; ++j) {
                    h2 r = __builtin_elementwise_fma(uu[j], cw.h, cb.h);
                    a1[j][ks].h[i] = __builtin_elementwise_max(r, z);
                }
            }
        }

        // ---- layer 2: nt-outer, dual accumulators sharing weight loads ----
        FR f3[2][7];
        #pragma unroll
        for (int nt = 0; nt < 4; ++nt) {
            f32x16 acc[2];
            #pragma unroll
            for (int r = 0; r < 16; ++r) { acc[0][r] = 0.f; acc[1][r] = 0.f; }
            #pragma unroll
            for (int ks = 0; ks < 7; ++ks) {
                f16x8 wA = *(const f16x8*)(W1f + ((nt * 7 + ks) << 9) + zoff);
                acc[0] = __builtin_amdgcn_mfma_f32_32x32x16_f16(wA, a1[0][ks].v, acc[0], 0, 0, 0);
                acc[1] = __builtin_amdgcn_mfma_f32_32x32x16_f16(wA, a1[1][ks].v, acc[1], 0, 0, 0);
            }
            #pragma unroll
            for (int j = 0; j < 2; ++j) {
                if (nt < 3) {
                    unsigned int pk[4][2];
                    #pragma unroll
                    for (int qi = 0; qi < 4; ++qi) {
                        f32x2 lo = {acc[j][4 * qi + 0], acc[j][4 * qi + 1]};
                        f32x2 hi = {acc[j][4 * qi + 2], acc[j][4 * qi + 3]};
                        lo = __builtin_elementwise_max(lo, zero2);   // v_pk_max_f32
                        hi = __builtin_elementwise_max(hi, zero2);
                        pk[qi][0] = hpk(lo[0], lo[1]);
                        pk[qi][1] = hpk(hi[0], hi[1]);
                    }
                    #pragma unroll
                    for (int kk = 0; kk < 2; ++kk) {
                        unsigned int X0 = hfb ? pk[2 * kk][0] : pk[2 * kk + 1][0];
                        unsigned int X1 = hfb ? pk[2 * kk][1] : pk[2 * kk + 1][1];
                        unsigned int O0 = hfb ? pk[2 * kk + 1][0] : pk[2 * kk][0];
                        unsigned int O1 = hfb ? pk[2 * kk + 1][1] : pk[2 * kk][1];
                        unsigned int Y0 = (unsigned int)__shfl_xor((int)X0, 32, 64);
                        unsigned int Y1 = (unsigned int)__shfl_xor((int)X1, 32, 64);
                        f3[j][nt * 2 + kk].u32[0] = hfb ? Y0 : O0;
                        f3[j][nt * 2 + kk].u32[1] = hfb ? Y1 : O1;
                        f3[j][nt * 2 + kk].u32[2] = hfb ? O0 : Y0;
                        f3[j][nt * 2 + kk].u32[3] = hfb ? O1 : Y1;
                    }
                } else {
                    // nt=3 tile: only rows 96..99 real; only hf0 readers consume.
                    f32x2 lo = {acc[j][0], acc[j][1]};
                    f32x2 hi = {acc[j][2], acc[j][3]};
                    lo = __builtin_elementwise_max(lo, zero2);
                    hi = __builtin_elementwise_max(hi, zero2);
                    unsigned int p0 = hpk(lo[0], lo[1]);
                    unsigned int p1 = hpk(hi[0], hi[1]);
                    f3[j][6].u32[0] = hfb ? 0u : p0;
                    f3[j][6].u32[1] = hfb ? 0u : p1;
                    f3[j][6].u32[2] = hfb ? 0u : 0x00003C00u;   // f16 1.0
                    f3[j][6].u32[3] = 0u;
                }
            }
        }

        // ---- layer 3: nt2-outer, dual accumulators; shared W2 + w3 loads ----
        f32x2 oacc2[2] = {{0.f, 0.f}, {0.f, 0.f}};
        #pragma unroll
        for (int nt2 = 0; nt2 < 4; ++nt2) {
            f32x16 acc2[2];
            #pragma unroll
            for (int r = 0; r < 16; ++r) { acc2[0][r] = 0.f; acc2[1][r] = 0.f; }
            #pragma unroll
            for (int ks = 0; ks < 7; ++ks) {
                f16x8 wA = *(const f16x8*)(W2f + ((nt2 * 7 + ks) << 9) + zoff);
                acc2[0] = __builtin_amdgcn_mfma_f32_32x32x16_f16(wA, f3[0][ks].v, acc2[0], 0, 0, 0);
                acc2[1] = __builtin_amdgcn_mfma_f32_32x32x16_f16(wA, f3[1][ks].v, acc2[1], 0, 0, 0);
            }
            uint4 wa = *(const uint4*)&w3p_s[hf * 32 + nt2 * 8 + zoff];
            uint4 wb2 = *(const uint4*)&w3p_s[hf * 32 + nt2 * 8 + 4 + zoff];
            unsigned int w8[8] = {wa.x, wa.y, wa.z, wa.w, wb2.x, wb2.y, wb2.z, wb2.w};
            f32x2 w3v[8];
            #pragma unroll
            for (int q = 0; q < 8; ++q) {
                w3v[q][0] = __uint_as_float(w8[q] << 16);
                w3v[q][1] = __uint_as_float(w8[q] & 0xFFFF0000u);
            }
            #pragma unroll
            for (int j = 0; j < 2; ++j)
                #pragma unroll
                for (int qi = 0; qi < 4; ++qi) {
                    f32x2 lo = {acc2[j][4 * qi + 0], acc2[j][4 * qi + 1]};
                    f32x2 hi = {acc2[j][4 * qi + 2], acc2[j][4 * qi + 3]};
                    lo = __builtin_elementwise_max(lo, zero2);          // v_pk_max_f32
                    hi = __builtin_elementwise_max(hi, zero2);
                    oacc2[j] = __builtin_elementwise_fma(lo, w3v[qi * 2], oacc2[j]);      // v_pk_fma_f32
                    oacc2[j] = __builtin_elementwise_fma(hi, w3v[qi * 2 + 1], oacc2[j]);
                }
        }

        // ---- epilogue x2: elu+1, quadrature weight, segmented reduce ----
        #pragma unroll
        for (int j = 0; j < 2; ++j) {
            float oacc = oacc2[j][0] + oacc2[j][1];
            float o = oacc + __shfl_xor(oacc, 32, 64) + b3;
            float dz = (o > 0.f) ? (o + 1.f) : expf(o);   // elu(o) + 1
            float val = dz * ccw_s[p[j]];
            int nA = __shfl(nloc[j], 0, 32);
            int nB = __shfl(nloc[j], 31, 32);
            float vA = (nloc[j] == nA) ? val : 0.f;
            vA += __shfl_xor(vA, 16, 32);
            vA += __shfl_xor(vA, 8, 32);
            vA += __shfl_xor(vA, 4, 32);
            vA += __shfl_xor(vA, 2, 32);
            vA += __shfl_xor(vA, 1, 32);
            if (lane == 0) atomicAdd(&zs[nA], vA);
            if (nB != nA) {
                float vB = (nloc[j] == nB) ? val : 0.f;
                vB += __shfl_xor(vB, 16, 32);
                vB += __shfl_xor(vB, 8, 32);
                vB += __shfl_xor(vB, 4, 32);
                vB += __shfl_xor(vB, 2, 32);
                vB += __shfl_xor(vB, 1, 32);
                if (lane == 1) atomicAdd(&zs[nB], vB);
            }
        }
    }

    __syncthreads();
    if (tid < SPB) {
        int n = blockIdx.x * SPB + tid;
        if (n < nTot) dst[n] = fmaf(e1, 0.5f * xs_s[tid] * zs[tid], o0);
    }
}

extern "C" void kernel_launch(void* const* d_in, const int* in_sizes, int n_in,
                              void* d_out, int out_size, void* d_ws, size_t ws_size,
                              hipStream_t stream)
{
    const float* logits = (const float*)d_in[0];
    const float* iW0 = (const float*)d_in[2];
    const float* ib0 = (const float*)d_in[3];
    const float* iW1 = (const float*)d_in[4];
    const float* ib1 = (const float*)d_in[5];
    const float* iW2 = (const float*)d_in[6];
    const float* ib2 = (const float*)d_in[7];
    const float* iW3 = (const float*)d_in[8];
    const float* ib3 = (const float*)d_in[9];
    const float* hb0 = (const float*)d_in[11];
    const float* hW1 = (const float*)d_in[12];
    const float* hb1 = (const float*)d_in[13];
    const float* hW2 = (const float*)d_in[14];
    const float* hb2 = (const float*)d_in[15];
    const float* hW3 = (const float*)d_in[16];
    const float* hb3 = (const float*)d_in[17];
    float* out = (float*)d_out;
    float* ws = (float*)d_ws;
    int n = in_sizes[0];
    int nblocks = (n + SPB - 1) / SPB;

    hipLaunchKernelGGL(setup_kernel, dim3(64), dim3(256), 0, stream,
                       logits, iW1, ib1, iW2, ib2,
                       hb0, hW1, hb1, hW2, hb2, hW3, hb3, ws, out + 2 * n, n);
    // phase A: k=0 -> x2 (workspace), k=1 -> y1
    hipLaunchKernelGGL(mono_mfma, dim3(nblocks, 2), dim3(256), 0, stream,
                       logits, iW0, ib0, iW3, ib3, ws,
                       ws + WS_X2, out, 0, n);
    // phase B: k=2 on x2 -> y2
    hipLaunchKernelGGL(mono_mfma, dim3(nblocks, 1), dim3(256), 0, stream,
                       ws + WS_X2, iW0, ib0, iW3, ib3, ws,
                       out + n, out + n, 2, n);
}

// Round 13
// 179.444 us; speedup vs baseline: 2.9697x; 2.9697x over previous
//
#include <hip/hip_runtime.h>
#include <hip/hip_bf16.h>
#include <hip/hip_fp16.h>
#include <math.h>

typedef _Float16 f16x8 __attribute__((ext_vector_type(8)));
typedef _Float16 h2 __attribute__((ext_vector_type(2)));
typedef __fp16 h2amd __attribute__((ext_vector_type(2)));   // builtin return type
typedef float f32x16 __attribute__((ext_vector_type(16)));
typedef float f32x2 __attribute__((ext_vector_type(2)));

#define DH 100      // hidden dim
#define G  4096     // table size per net
#define NITB 2      // build: iterations per block (keeps laundering effective)
#define WSTR 120    // LDS row stride in f16 elems

// ws float offsets
#define WS_CCW   0      // [0,128)
#define WS_XSC   128    // [128,256)
#define WS_OH0   256    // 3
#define WS_EOH1  260    // 3
#define WS_P01   264    // 64 min/max pairs (logits)
#define WS_P2    392    // 64 min/max pairs (x2)
#define WS_X2    1024   // [1024, 1024+N)
#define WS_TAB   17408  // 3*G table floats

__device__ __forceinline__ unsigned short f2bf(float f) {
    unsigned int u = __float_as_uint(f);
    unsigned int r = (u + 0x7FFFu + ((u >> 16) & 1u)) >> 16;  // RNE
    return (unsigned short)r;
}
__device__ __forceinline__ unsigned int hpk(float a, float b) {
    union { h2amd h; unsigned int u; } c;
    c.h = __builtin_amdgcn_cvt_pkrtz(a, b);
    return c.u;
}
__device__ __forceinline__ h2 hpk2(float a, float b) {
    union { h2amd ha; h2 h; } c;
    c.ha = __builtin_amdgcn_cvt_pkrtz(a, b);
    return c.h;
}

// prep: quadrature consts (block 3), h-MLP consts (blocks 0-2, one net each,
// LDS-staged weights), logits passthrough + per-block min/max partials (all).
__global__ __launch_bounds__(256)
void prep_kernel(const float* __restrict__ logits,
                 const float* __restrict__ hb0,
                 const float* __restrict__ hW1, const float* __restrict__ hb1,
                 const float* __restrict__ hW2, const float* __restrict__ hb2,
                 const float* __restrict__ hW3, const float* __restrict__ hb3,
                 float* __restrict__ ws, float* __restrict__ out2, int n)
{
    __shared__ float hw_s[DH * 101];
    __shared__ float bufA[128], bufB[128];
    __shared__ float rmin_s[4], rmax_s[4];
    const int t = threadIdx.x;
    const int b = blockIdx.x;

    float lmin = 1e30f, lmax = -1e30f;
    for (int i = b * 256 + t; i < n; i += gridDim.x * 256) {
        float v = logits[i];
        out2[i] = v;
        lmin = fminf(lmin, v);
        lmax = fmaxf(lmax, v);
    }
    #pragma unroll
    for (int off = 1; off < 64; off <<= 1) {
        lmin = fminf(lmin, __shfl_xor(lmin, off, 64));
        lmax = fmaxf(lmax, __shfl_xor(lmax, off, 64));
    }
    if ((t & 63) == 0) { rmin_s[t >> 6] = lmin; rmax_s[t >> 6] = lmax; }
    __syncthreads();
    if (t == 0) {
        float m = fminf(fminf(rmin_s[0], rmin_s[1]), fminf(rmin_s[2], rmin_s[3]));
        float M = fmaxf(fmaxf(rmax_s[0], rmax_s[1]), fmaxf(rmax_s[2], rmax_s[3]));
        ws[WS_P01 + 2 * b] = m;
        ws[WS_P01 + 2 * b + 1] = M;
    }

    if (b == 3) {
        if (t < 128) {
            double ccw = 0.0, xs = 0.0;
            if (t <= 100) {
                double s = (double)t;
                for (int j = 0; j <= 100; j += 2) {
                    double wj = (j == 0) ? 1.0 : 2.0 / (1.0 - (double)j * (double)j);
                    double lam;
                    if (t == 0) lam = 0.5;
                    else {
                        lam = cos((double)j * s * M_PI / 100.0);
                        if (t == 100) lam *= 0.5;
                    }
                    ccw += lam * 0.02 * wj;
                }
                xs = (cos(s * M_PI / 100.0) + 1.0) * 0.5;
            }
            ws[WS_CCW + t] = (float)ccw;
            ws[WS_XSC + t] = (float)xs;
        }
    } else if (b < 3) {
        const int k = b;                       // one net per block
        if (t < 128) bufA[t] = (t < DH) ? fmaxf(hb0[k * DH + t], 0.f) : 0.f;
        __syncthreads();
        for (int i = t; i < DH * DH; i += 256) {
            int r = i / DH, c = i - r * DH;
            hw_s[r * 101 + c] = hW1[k * DH * DH + i];
        }
        __syncthreads();
        if (t < DH) {
            float acc = hb1[k * DH + t];
            for (int i = 0; i < DH; ++i) acc = fmaf(hw_s[t * 101 + i], bufA[i], acc);
            bufB[t] = fmaxf(acc, 0.f);
        }
        __syncthreads();
        for (int i = t; i < DH * DH; i += 256) {
            int r = i / DH, c = i - r * DH;
            hw_s[r * 101 + c] = hW2[k * DH * DH + i];
        }
        __syncthreads();
        if (t < DH) {
            float acc = hb2[k * DH + t];
            for (int i = 0; i < DH; ++i) acc = fmaf(hw_s[t * 101 + i], bufB[i], acc);
            bufA[t] = fmaxf(acc, 0.f);
        }
        __syncthreads();
        if (t < 2) {
            float acc = hb3[k * 2 + t];
            const float* w = hW3 + (size_t)(k * 2 + t) * DH;
            for (int i = 0; i < DH; ++i) acc = fmaf(w[i], bufA[i], acc);
            if (t == 0) ws[WS_OH0 + k] = acc;
            else        ws[WS_EOH1 + k] = expf(acc);
        }
    }
}

// build_tab: evaluate g_k(u) = elu(MLP_k(u))+1 on a G-point grid spanning the
// input range (reduced from per-block partials), using the R3-R11-verified
// transposed MFMA dataflow (lane^32 exchange, laundered LDS reads).
__global__ __launch_bounds__(256)
void build_tab(const float* __restrict__ iW0, const float* __restrict__ ib0,
               const float* __restrict__ iW1, const float* __restrict__ ib1,
               const float* __restrict__ iW2, const float* __restrict__ ib2,
               const float* __restrict__ iW3, const float* __restrict__ ib3,
               float* __restrict__ ws, const float* __restrict__ parts,
               int np, int kbase)
{
    __shared__ __align__(16) _Float16 W1s[DH * WSTR];
    __shared__ __align__(16) _Float16 W2s[DH * WSTR];
    __shared__ unsigned int w0p_s[64], b0p_s[64], w3p_s[64];
    __shared__ float u0_s, dlt_s;

    const int tid = threadIdx.x;
    const int lane = tid & 63;
    const int wv = tid >> 6;
    const int hf = lane >> 5;
    const bool hfb = (hf != 0);
    const int l31 = lane & 31;
    const int k = kbase + blockIdx.y;
    float* __restrict__ tab = ws + WS_TAB + k * G;

    const float* W1g = iW1 + (size_t)k * DH * DH;
    const float* W2g = iW2 + (size_t)k * DH * DH;

    if (tid < 64) {
        float pm = 1e30f, pM = -1e30f;
        for (int i = tid; i < np; i += 64) {
            pm = fminf(pm, parts[2 * i]);
            pM = fmaxf(pM, parts[2 * i + 1]);
        }
        #pragma unroll
        for (int off = 1; off < 64; off <<= 1) {
            pm = fminf(pm, __shfl_xor(pm, off, 64));
            pM = fmaxf(pM, __shfl_xor(pM, off, 64));
        }
        if (tid == 0) {
            float um = fminf(pm, 0.f), uM = fmaxf(pM, 0.f);
            float span = fmaxf(uM - um, 1e-5f);
            u0_s = um;
            dlt_s = span * (1.f / (float)(G - 1));
        }

        int s0 = 2 * tid, s1 = 2 * tid + 1;
        float w0a = (s0 < DH) ? iW0[(k * DH + s0) * 3] : 0.f;   // h==0: feature 0 only
        float w0b = (s1 < DH) ? iW0[(k * DH + s1) * 3] : 0.f;
        float b0a = (s0 < DH) ? ib0[k * DH + s0] : ((s0 == DH) ? 1.f : 0.f);
        float b0b = (s1 < DH) ? ib0[k * DH + s1] : 0.f;
        w0p_s[tid] = hpk(w0a, w0b);
        b0p_s[tid] = hpk(b0a, b0b);

        int hf_i = tid >> 5, rem = tid & 31;
        int nt2 = rem >> 3, qq = (rem >> 1) & 3, pr = rem & 1;
        int n2e = 32 * nt2 + 8 * qq + 2 * pr + 4 * hf_i;
        float we = (n2e < DH) ? iW3[k * DH + n2e] : 0.f;
        float wo = (n2e + 1 < DH) ? iW3[k * DH + n2e + 1] : 0.f;
        w3p_s[tid] = ((unsigned int)f2bf(wo) << 16) | (unsigned int)f2bf(we);
    }
    for (int i = tid; i < DH * WSTR; i += 256) {
        int r = i / WSTR, c = i - r * WSTR;
        float v1, v2;
        if (c < DH)       { v1 = W1g[r * DH + c]; v2 = W2g[r * DH + c]; }
        else if (c == DH) { v1 = ib1[k * DH + r]; v2 = ib2[k * DH + r]; }
        else              { v1 = 0.f; v2 = 0.f; }
        W1s[r * WSTR + c] = (_Float16)v1;
        W2s[r * WSTR + c] = (_Float16)v2;
    }
    __syncthreads();

    const float b3 = ib3[k];
    const float u0 = u0_s, dlt = dlt_s;

    int wrow[4];
    #pragma unroll
    for (int nt = 0; nt < 4; ++nt) {
        int r = nt * 32 + l31;
        wrow[nt] = ((r > DH - 1) ? (DH - 1) : r) * WSTR + hf * 8;
    }

    union FR { f16x8 v; h2 h[4]; unsigned int u32[4]; };
    const f32x2 zero2 = {0.f, 0.f};

    #pragma unroll 1
    for (int it = 0; it < NITB; ++it) {
        unsigned int zoff = 0;
        asm volatile("" : "+v"(zoff));   // block LICM register caching

        int mr[2];
        h2 uu[2];
        #pragma unroll
        for (int j = 0; j < 2; ++j) {
            mr[j] = (blockIdx.x * NITB + it) * 256 + j * 128 + wv * 32 + l31;
            float u = fmaf((float)mr[j], dlt, u0);
            uu[j] = hpk2(u, u);
        }

        // layer 1: B-frags for both row groups, shared w0/b0 loads
        FR a1[2][7];
        #pragma unroll
        for (int ks = 0; ks < 7; ++ks) {
            int pb = ks * 8 + hf * 4 + zoff;
            uint4 wq = *(const uint4*)&w0p_s[pb];
            uint4 bq = *(const uint4*)&b0p_s[pb];
            unsigned int wqa[4] = {wq.x, wq.y, wq.z, wq.w};
            unsigned int bqa[4] = {bq.x, bq.y, bq.z, bq.w};
            #pragma unroll
            for (int i = 0; i < 4; ++i) {
                union { unsigned int u; h2 h; } cw, cb;
                cw.u = wqa[i]; cb.u = bqa[i];
                h2 z = {(_Float16)0.f, (_Float16)0.f};
                #pragma unroll
                for (int j = 0; j < 2; ++j) {
                    h2 r = __builtin_elementwise_fma(uu[j], cw.h, cb.h);
                    a1[j][ks].h[i] = __builtin_elementwise_max(r, z);
                }
            }
        }

        // layer 2: dual accumulators share weight loads; pack+exchange -> f3
        FR f3[2][7];
        #pragma unroll
        for (int nt = 0; nt < 4; ++nt) {
            f32x16 acc[2];
            #pragma unroll
            for (int r = 0; r < 16; ++r) { acc[0][r] = 0.f; acc[1][r] = 0.f; }
            #pragma unroll
            for (int ks = 0; ks < 7; ++ks) {
                f16x8 wA = *(const f16x8*)&W1s[wrow[nt] + ks * 16 + zoff];
                acc[0] = __builtin_amdgcn_mfma_f32_32x32x16_f16(wA, a1[0][ks].v, acc[0], 0, 0, 0);
                acc[1] = __builtin_amdgcn_mfma_f32_32x32x16_f16(wA, a1[1][ks].v, acc[1], 0, 0, 0);
            }
            #pragma unroll
            for (int j = 0; j < 2; ++j) {
                if (nt < 3) {
                    unsigned int pk[4][2];
                    #pragma unroll
                    for (int qi = 0; qi < 4; ++qi) {
                        f32x2 lo = {acc[j][4 * qi + 0], acc[j][4 * qi + 1]};
                        f32x2 hi = {acc[j][4 * qi + 2], acc[j][4 * qi + 3]};
                        lo = __builtin_elementwise_max(lo, zero2);
                        hi = __builtin_elementwise_max(hi, zero2);
                        pk[qi][0] = hpk(lo[0], lo[1]);
                        pk[qi][1] = hpk(hi[0], hi[1]);
                    }
                    #pragma unroll
                    for (int kk = 0; kk < 2; ++kk) {
                        unsigned int X0 = hfb ? pk[2 * kk][0] : pk[2 * kk + 1][0];
                        unsigned int X1 = hfb ? pk[2 * kk][1] : pk[2 * kk + 1][1];
                        unsigned int O0 = hfb ? pk[2 * kk + 1][0] : pk[2 * kk][0];
                        unsigned int O1 = hfb ? pk[2 * kk + 1][1] : pk[2 * kk][1];
                        unsigned int Y0 = (unsigned int)__shfl_xor((int)X0, 32, 64);
                        unsigned int Y1 = (unsigned int)__shfl_xor((int)X1, 32, 64);
                        f3[j][nt * 2 + kk].u32[0] = hfb ? Y0 : O0;
                        f3[j][nt * 2 + kk].u32[1] = hfb ? Y1 : O1;
                        f3[j][nt * 2 + kk].u32[2] = hfb ? O0 : Y0;
                        f3[j][nt * 2 + kk].u32[3] = hfb ? O1 : Y1;
                    }
                } else {
                    f32x2 lo = {acc[j][0], acc[j][1]};
                    f32x2 hi = {acc[j][2], acc[j][3]};
                    lo = __builtin_elementwise_max(lo, zero2);
                    hi = __builtin_elementwise_max(hi, zero2);
                    unsigned int p0 = hpk(lo[0], lo[1]);
                    unsigned int p1 = hpk(hi[0], hi[1]);
                    f3[j][6].u32[0] = hfb ? 0u : p0;
                    f3[j][6].u32[1] = hfb ? 0u : p1;
                    f3[j][6].u32[2] = hfb ? 0u : 0x00003C00u;   // f16 1.0 (bias slot)
                    f3[j][6].u32[3] = 0u;
                }
            }
        }

        // layer 3: dual accumulators; shared W2 + w3 loads; fold w3
        f32x2 oacc2[2] = {{0.f, 0.f}, {0.f, 0.f}};
        #pragma unroll
        for (int nt2 = 0; nt2 < 4; ++nt2) {
            f32x16 acc2[2];
            #pragma unroll
            for (int r = 0; r < 16; ++r) { acc2[0][r] = 0.f; acc2[1][r] = 0.f; }
            #pragma unroll
            for (int ks = 0; ks < 7; ++ks) {
                f16x8 wA = *(const f16x8*)&W2s[wrow[nt2] + ks * 16 + zoff];
                acc2[0] = __builtin_amdgcn_mfma_f32_32x32x16_f16(wA, f3[0][ks].v, acc2[0], 0, 0, 0);
                acc2[1] = __builtin_amdgcn_mfma_f32_32x32x16_f16(wA, f3[1][ks].v, acc2[1], 0, 0, 0);
            }
            uint4 wa = *(const uint4*)&w3p_s[hf * 32 + nt2 * 8 + zoff];
            uint4 wb2 = *(const uint4*)&w3p_s[hf * 32 + nt2 * 8 + 4 + zoff];
            unsigned int w8[8] = {wa.x, wa.y, wa.z, wa.w, wb2.x, wb2.y, wb2.z, wb2.w};
            f32x2 w3v[8];
            #pragma unroll
            for (int q = 0; q < 8; ++q) {
                w3v[q][0] = __uint_as_float(w8[q] << 16);
                w3v[q][1] = __uint_as_float(w8[q] & 0xFFFF0000u);
            }
            #pragma unroll
            for (int j = 0; j < 2; ++j)
                #pragma unroll
                for (int qi = 0; qi < 4; ++qi) {
                    f32x2 lo = {acc2[j][4 * qi + 0], acc2[j][4 * qi + 1]};
                    f32x2 hi = {acc2[j][4 * qi + 2], acc2[j][4 * qi + 3]};
                    lo = __builtin_elementwise_max(lo, zero2);
                    hi = __builtin_elementwise_max(hi, zero2);
                    oacc2[j] = __builtin_elementwise_fma(lo, w3v[qi * 2], oacc2[j]);
                    oacc2[j] = __builtin_elementwise_fma(hi, w3v[qi * 2 + 1], oacc2[j]);
                }
        }

        #pragma unroll
        for (int j = 0; j < 2; ++j) {
            float oacc = oacc2[j][0] + oacc2[j][1];
            float o = oacc + __shfl_xor(oacc, 32, 64) + b3;
            float dz = (o > 0.f) ? (o + 1.f) : expf(o);   // elu(o) + 1
            if (!hfb) tab[mr[j]] = dz;
        }
    }
}

// eval_z: per sample, z = sum_p ccw[p] * lerp(tab_k, x*xsc[p]); y = e1*0.5*x*z + o0.
__global__ __launch_bounds__(256)
void eval_z(const float* __restrict__ src0, float* __restrict__ dst0,
            const float* __restrict__ src1, float* __restrict__ dst1,
            const float* __restrict__ ws, const float* __restrict__ parts,
            float* __restrict__ partsOut, int np, int kbase, int n)
{
    __shared__ float tab_s[G];
    __shared__ float xsc_s[104], ccw_s[104];
    __shared__ float u0_s, inv_s, rmin_s[4], rmax_s[4];

    const int tid = threadIdx.x;
    const int lane = tid & 63;
    const int wv = tid >> 6;
    const int k = kbase + blockIdx.y;
    const float* __restrict__ src = blockIdx.y ? src1 : src0;
    float* __restrict__ dst = blockIdx.y ? dst1 : dst0;
    const bool doParts = (partsOut != 0) && (blockIdx.y == 0);

    const float* tg = ws + WS_TAB + k * G;
    for (int i = tid; i < G; i += 256) tab_s[i] = tg[i];
    if (tid < 104) {
        xsc_s[tid] = (tid < 101) ? ws[WS_XSC + tid] : 0.f;
        ccw_s[tid] = (tid < 101) ? ws[WS_CCW + tid] : 0.f;
    }
    if (tid < 64) {
        float pm = 1e30f, pM = -1e30f;
        for (int i = tid; i < np; i += 64) {
            pm = fminf(pm, parts[2 * i]);
            pM = fmaxf(pM, parts[2 * i + 1]);
        }
        #pragma unroll
        for (int off = 1; off < 64; off <<= 1) {
            pm = fminf(pm, __shfl_xor(pm, off, 64));
            pM = fmaxf(pM, __shfl_xor(pM, off, 64));
        }
        if (tid == 0) {
            float um = fminf(pm, 0.f), uM = fmaxf(pM, 0.f);
            float span = fmaxf(uM - um, 1e-5f);
            u0_s = um;
            inv_s = (float)(G - 1) / span;
        }
    }
    __syncthreads();

    const float u0 = u0_s, invd = inv_s;
    const int nn = blockIdx.x * 256 + tid;
    const float x = (nn < n) ? src[nn] : 0.f;
    float z = 0.f;
    for (int p = 0; p < 101; ++p) {
        float u = x * xsc_s[p];
        float tt = fminf(fmaxf((u - u0) * invd, 0.f), (float)(G - 1) - 0.001f);
        int i = (int)tt;
        float f = tt - (float)i;
        float g0 = tab_s[i];
        float g1 = tab_s[i + 1];
        z = fmaf(ccw_s[p], fmaf(f, g1 - g0, g0), z);
    }
    const float e1 = ws[WS_EOH1 + k];
    const float o0 = ws[WS_OH0 + k];
    float y = fmaf(e1, 0.5f * x * z, o0);
    if (nn < n) dst[nn] = y;

    if (doParts) {
        float ymin = (nn < n) ? y : 1e30f;
        float ymax = (nn < n) ? y : -1e30f;
        #pragma unroll
        for (int off = 1; off < 64; off <<= 1) {
            ymin = fminf(ymin, __shfl_xor(ymin, off, 64));
            ymax = fmaxf(ymax, __shfl_xor(ymax, off, 64));
        }
        if (lane == 0) { rmin_s[wv] = ymin; rmax_s[wv] = ymax; }
        __syncthreads();
        if (tid == 0) {
            float m = fminf(fminf(rmin_s[0], rmin_s[1]), fminf(rmin_s[2], rmin_s[3]));
            float M = fmaxf(fmaxf(rmax_s[0], rmax_s[1]), fmaxf(rmax_s[2], rmax_s[3]));
            partsOut[2 * blockIdx.x] = m;
            partsOut[2 * blockIdx.x + 1] = M;
        }
    }
}

extern "C" void kernel_launch(void* const* d_in, const int* in_sizes, int n_in,
                              void* d_out, int out_size, void* d_ws, size_t ws_size,
                              hipStream_t stream)
{
    const float* logits = (const float*)d_in[0];
    const float* iW0 = (const float*)d_in[2];
    const float* ib0 = (const float*)d_in[3];
    const float* iW1 = (const float*)d_in[4];
    const float* ib1 = (const float*)d_in[5];
    const float* iW2 = (const float*)d_in[6];
    const float* ib2 = (const float*)d_in[7];
    const float* iW3 = (const float*)d_in[8];
    const float* ib3 = (const float*)d_in[9];
    const float* hb0 = (const float*)d_in[11];
    const float* hW1 = (const float*)d_in[12];
    const float* hb1 = (const float*)d_in[13];
    const float* hW2 = (const float*)d_in[14];
    const float* hb2 = (const float*)d_in[15];
    const float* hW3 = (const float*)d_in[16];
    const float* hb3 = (const float*)d_in[17];
    float* out = (float*)d_out;
    float* ws = (float*)d_ws;
    int n = in_sizes[0];
    int nbE = (n + 255) / 256;

    // 1) consts + logits passthrough + logits min/max partials (64 pairs)
    hipLaunchKernelGGL(prep_kernel, dim3(64), dim3(256), 0, stream,
                       logits, hb0, hW1, hb1, hW2, hb2, hW3, hb3, ws, out + 2 * n, n);
    // 2) tables for nets 0,1 over the logits-derived u-range
    hipLaunchKernelGGL(build_tab, dim3(G / (NITB * 256), 2), dim3(256), 0, stream,
                       iW0, ib0, iW1, ib1, iW2, ib2, iW3, ib3, ws, ws + WS_P01, 64, 0);
    // 3) eval k=0 -> x2 (+ x2 min/max partials), k=1 -> y1
    hipLaunchKernelGGL(eval_z, dim3(nbE, 2), dim3(256), 0, stream,
                       logits, ws + WS_X2, logits, out,
                       ws, ws + WS_P01, ws + WS_P2, 64, 0, n);
    // 4) table for net 2 over the x2-derived u-range
    hipLaunchKernelGGL(build_tab, dim3(G / (NITB * 256), 1), dim3(256), 0, stream,
                       iW0, ib0, iW1, ib1, iW2, ib2, iW3, ib3, ws, ws + WS_P2, nbE, 2);
    // 5) eval k=2 on x2 -> y2
    hipLaunchKernelGGL(eval_z, dim3(nbE, 1), dim3(256), 0, stream,
                       ws + WS_X2, out + n, ws + WS_X2, out + n,
                       ws, ws + WS_P2, (float*)0, nbE, 2, n);
}

// Round 14
// 164.404 us; speedup vs baseline: 3.2414x; 1.0915x over previous
//
#include <hip/hip_runtime.h>
#include <hip/hip_bf16.h>
#include <hip/hip_fp16.h>
#include <math.h>

typedef _Float16 f16x8 __attribute__((ext_vector_type(8)));
typedef _Float16 h2 __attribute__((ext_vector_type(2)));
typedef __fp16 h2amd __attribute__((ext_vector_type(2)));   // builtin return type
typedef float f32x16 __attribute__((ext_vector_type(16)));
typedef float f32x2 __attribute__((ext_vector_type(2)));

#define DH 100      // hidden dim
#define G  4096     // table size per net
#define WSTR 120    // LDS row stride in f16 elems
#define SPB_E 64    // eval: samples per block (4 threads/sample)

// ws float offsets
#define WS_CCW   0      // [0,128)
#define WS_XSC   128    // [128,256)
#define WS_OH0   256    // 3
#define WS_EOH1  260    // 3
#define WS_P01   264    // 64 min/max pairs (logits)  [264,392)
#define WS_P2    392    // up to 256 min/max pairs (x2) [392,904)
#define WS_X2    1024   // [1024, 1024+N)
#define WS_TAB   17408  // 3*G table floats

__device__ __forceinline__ unsigned short f2bf(float f) {
    unsigned int u = __float_as_uint(f);
    unsigned int r = (u + 0x7FFFu + ((u >> 16) & 1u)) >> 16;  // RNE
    return (unsigned short)r;
}
__device__ __forceinline__ unsigned int hpk(float a, float b) {
    union { h2amd h; unsigned int u; } c;
    c.h = __builtin_amdgcn_cvt_pkrtz(a, b);
    return c.u;
}
__device__ __forceinline__ h2 hpk2(float a, float b) {
    union { h2amd ha; h2 h; } c;
    c.ha = __builtin_amdgcn_cvt_pkrtz(a, b);
    return c.h;
}

// prep: quadrature consts (block 3), h-MLP consts (blocks 0-2, one net each,
// LDS-staged weights), logits passthrough + per-block min/max partials (all).
__global__ __launch_bounds__(256)
void prep_kernel(const float* __restrict__ logits,
                 const float* __restrict__ hb0,
                 const float* __restrict__ hW1, const float* __restrict__ hb1,
                 const float* __restrict__ hW2, const float* __restrict__ hb2,
                 const float* __restrict__ hW3, const float* __restrict__ hb3,
                 float* __restrict__ ws, float* __restrict__ out2, int n)
{
    __shared__ float hw_s[DH * 101];
    __shared__ float bufA[128], bufB[128];
    __shared__ float rmin_s[4], rmax_s[4];
    const int t = threadIdx.x;
    const int b = blockIdx.x;

    float lmin = 1e30f, lmax = -1e30f;
    for (int i = b * 256 + t; i < n; i += gridDim.x * 256) {
        float v = logits[i];
        out2[i] = v;
        lmin = fminf(lmin, v);
        lmax = fmaxf(lmax, v);
    }
    #pragma unroll
    for (int off = 1; off < 64; off <<= 1) {
        lmin = fminf(lmin, __shfl_xor(lmin, off, 64));
        lmax = fmaxf(lmax, __shfl_xor(lmax, off, 64));
    }
    if ((t & 63) == 0) { rmin_s[t >> 6] = lmin; rmax_s[t >> 6] = lmax; }
    __syncthreads();
    if (t == 0) {
        float m = fminf(fminf(rmin_s[0], rmin_s[1]), fminf(rmin_s[2], rmin_s[3]));
        float M = fmaxf(fmaxf(rmax_s[0], rmax_s[1]), fmaxf(rmax_s[2], rmax_s[3]));
        ws[WS_P01 + 2 * b] = m;
        ws[WS_P01 + 2 * b + 1] = M;
    }

    if (b == 3) {
        if (t < 128) {
            double ccw = 0.0, xs = 0.0;
            if (t <= 100) {
                double s = (double)t;
                for (int j = 0; j <= 100; j += 2) {
                    double wj = (j == 0) ? 1.0 : 2.0 / (1.0 - (double)j * (double)j);
                    double lam;
                    if (t == 0) lam = 0.5;
                    else {
                        lam = cos((double)j * s * M_PI / 100.0);
                        if (t == 100) lam *= 0.5;
                    }
                    ccw += lam * 0.02 * wj;
                }
                xs = (cos(s * M_PI / 100.0) + 1.0) * 0.5;
            }
            ws[WS_CCW + t] = (float)ccw;
            ws[WS_XSC + t] = (float)xs;
        }
    } else if (b < 3) {
        const int k = b;                       // one net per block
        if (t < 128) bufA[t] = (t < DH) ? fmaxf(hb0[k * DH + t], 0.f) : 0.f;
        __syncthreads();
        for (int i = t; i < DH * DH; i += 256) {
            int r = i / DH, c = i - r * DH;
            hw_s[r * 101 + c] = hW1[k * DH * DH + i];
        }
        __syncthreads();
        if (t < DH) {
            float acc = hb1[k * DH + t];
            for (int i = 0; i < DH; ++i) acc = fmaf(hw_s[t * 101 + i], bufA[i], acc);
            bufB[t] = fmaxf(acc, 0.f);
        }
        __syncthreads();
        for (int i = t; i < DH * DH; i += 256) {
            int r = i / DH, c = i - r * DH;
            hw_s[r * 101 + c] = hW2[k * DH * DH + i];
        }
        __syncthreads();
        if (t < DH) {
            float acc = hb2[k * DH + t];
            for (int i = 0; i < DH; ++i) acc = fmaf(hw_s[t * 101 + i], bufB[i], acc);
            bufA[t] = fmaxf(acc, 0.f);
        }
        __syncthreads();
        if (t < 2) {
            float acc = hb3[k * 2 + t];
            const float* w = hW3 + (size_t)(k * 2 + t) * DH;
            for (int i = 0; i < DH; ++i) acc = fmaf(w[i], bufA[i], acc);
            if (t == 0) ws[WS_OH0 + k] = acc;
            else        ws[WS_EOH1 + k] = expf(acc);
        }
    }
}

// build_tab: evaluate g_k(u) = elu(MLP_k(u))+1 on a G-point grid spanning the
// input range (reduced from per-block partials), using the R3-R11-verified
// transposed MFMA dataflow (lane^32 exchange, laundered LDS reads).
// One iteration (256 rows) per block -> G/256 blocks per net.
__global__ __launch_bounds__(256)
void build_tab(const float* __restrict__ iW0, const float* __restrict__ ib0,
               const float* __restrict__ iW1, const float* __restrict__ ib1,
               const float* __restrict__ iW2, const float* __restrict__ ib2,
               const float* __restrict__ iW3, const float* __restrict__ ib3,
               float* __restrict__ ws, const float* __restrict__ parts,
               int np, int kbase)
{
    __shared__ __align__(16) _Float16 W1s[DH * WSTR];
    __shared__ __align__(16) _Float16 W2s[DH * WSTR];
    __shared__ unsigned int w0p_s[64], b0p_s[64], w3p_s[64];
    __shared__ float u0_s, dlt_s;

    const int tid = threadIdx.x;
    const int lane = tid & 63;
    const int wv = tid >> 6;
    const int hf = lane >> 5;
    const bool hfb = (hf != 0);
    const int l31 = lane & 31;
    const int k = kbase + blockIdx.y;
    float* __restrict__ tab = ws + WS_TAB + k * G;

    const float* W1g = iW1 + (size_t)k * DH * DH;
    const float* W2g = iW2 + (size_t)k * DH * DH;

    if (tid < 64) {
        float pm = 1e30f, pM = -1e30f;
        for (int i = tid; i < np; i += 64) {
            pm = fminf(pm, parts[2 * i]);
            pM = fmaxf(pM, parts[2 * i + 1]);
        }
        #pragma unroll
        for (int off = 1; off < 64; off <<= 1) {
            pm = fminf(pm, __shfl_xor(pm, off, 64));
            pM = fmaxf(pM, __shfl_xor(pM, off, 64));
        }
        if (tid == 0) {
            float um = fminf(pm, 0.f), uM = fmaxf(pM, 0.f);
            float span = fmaxf(uM - um, 1e-5f);
            u0_s = um;
            dlt_s = span * (1.f / (float)(G - 1));
        }

        int s0 = 2 * tid, s1 = 2 * tid + 1;
        float w0a = (s0 < DH) ? iW0[(k * DH + s0) * 3] : 0.f;   // h==0: feature 0 only
        float w0b = (s1 < DH) ? iW0[(k * DH + s1) * 3] : 0.f;
        float b0a = (s0 < DH) ? ib0[k * DH + s0] : ((s0 == DH) ? 1.f : 0.f);
        float b0b = (s1 < DH) ? ib0[k * DH + s1] : 0.f;
        w0p_s[tid] = hpk(w0a, w0b);
        b0p_s[tid] = hpk(b0a, b0b);

        int hf_i = tid >> 5, rem = tid & 31;
        int nt2 = rem >> 3, qq = (rem >> 1) & 3, pr = rem & 1;
        int n2e = 32 * nt2 + 8 * qq + 2 * pr + 4 * hf_i;
        float we = (n2e < DH) ? iW3[k * DH + n2e] : 0.f;
        float wo = (n2e + 1 < DH) ? iW3[k * DH + n2e + 1] : 0.f;
        w3p_s[tid] = ((unsigned int)f2bf(wo) << 16) | (unsigned int)f2bf(we);
    }
    for (int i = tid; i < DH * WSTR; i += 256) {
        int r = i / WSTR, c = i - r * WSTR;
        float v1, v2;
        if (c < DH)       { v1 = W1g[r * DH + c]; v2 = W2g[r * DH + c]; }
        else if (c == DH) { v1 = ib1[k * DH + r]; v2 = ib2[k * DH + r]; }
        else              { v1 = 0.f; v2 = 0.f; }
        W1s[r * WSTR + c] = (_Float16)v1;
        W2s[r * WSTR + c] = (_Float16)v2;
    }
    __syncthreads();

    const float b3 = ib3[k];
    const float u0 = u0_s, dlt = dlt_s;

    int wrow[4];
    #pragma unroll
    for (int nt = 0; nt < 4; ++nt) {
        int r = nt * 32 + l31;
        wrow[nt] = ((r > DH - 1) ? (DH - 1) : r) * WSTR + hf * 8;
    }

    union FR { f16x8 v; h2 h[4]; unsigned int u32[4]; };
    const f32x2 zero2 = {0.f, 0.f};

    unsigned int zoff = 0;
    asm volatile("" : "+v"(zoff));   // opaque zero (keeps LDS reads un-cached)

    int mr[2];
    h2 uu[2];
    #pragma unroll
    for (int j = 0; j < 2; ++j) {
        mr[j] = blockIdx.x * 256 + j * 128 + wv * 32 + l31;
        float u = fmaf((float)mr[j], dlt, u0);
        uu[j] = hpk2(u, u);
    }

    // layer 1: B-frags for both row groups, shared w0/b0 loads
    FR a1[2][7];
    #pragma unroll
    for (int ks = 0; ks < 7; ++ks) {
        int pb = ks * 8 + hf * 4 + zoff;
        uint4 wq = *(const uint4*)&w0p_s[pb];
        uint4 bq = *(const uint4*)&b0p_s[pb];
        unsigned int wqa[4] = {wq.x, wq.y, wq.z, wq.w};
        unsigned int bqa[4] = {bq.x, bq.y, bq.z, bq.w};
        #pragma unroll
        for (int i = 0; i < 4; ++i) {
            union { unsigned int u; h2 h; } cw, cb;
            cw.u = wqa[i]; cb.u = bqa[i];
            h2 z = {(_Float16)0.f, (_Float16)0.f};
            #pragma unroll
            for (int j = 0; j < 2; ++j) {
                h2 r = __builtin_elementwise_fma(uu[j], cw.h, cb.h);
                a1[j][ks].h[i] = __builtin_elementwise_max(r, z);
            }
        }
    }

    // layer 2: dual accumulators share weight loads; pack+exchange -> f3
    FR f3[2][7];
    #pragma unroll
    for (int nt = 0; nt < 4; ++nt) {
        f32x16 acc[2];
        #pragma unroll
        for (int r = 0; r < 16; ++r) { acc[0][r] = 0.f; acc[1][r] = 0.f; }
        #pragma unroll
        for (int ks = 0; ks < 7; ++ks) {
            f16x8 wA = *(const f16x8*)&W1s[wrow[nt] + ks * 16 + zoff];
            acc[0] = __builtin_amdgcn_mfma_f32_32x32x16_f16(wA, a1[0][ks].v, acc[0], 0, 0, 0);
            acc[1] = __builtin_amdgcn_mfma_f32_32x32x16_f16(wA, a1[1][ks].v, acc[1], 0, 0, 0);
        }
        #pragma unroll
        for (int j = 0; j < 2; ++j) {
            if (nt < 3) {
                unsigned int pk[4][2];
                #pragma unroll
                for (int qi = 0; qi < 4; ++qi) {
                    f32x2 lo = {acc[j][4 * qi + 0], acc[j][4 * qi + 1]};
                    f32x2 hi = {acc[j][4 * qi + 2], acc[j][4 * qi + 3]};
                    lo = __builtin_elementwise_max(lo, zero2);
                    hi = __builtin_elementwise_max(hi, zero2);
                    pk[qi][0] = hpk(lo[0], lo[1]);
                    pk[qi][1] = hpk(hi[0], hi[1]);
                }
                #pragma unroll
                for (int kk = 0; kk < 2; ++kk) {
                    unsigned int X0 = hfb ? pk[2 * kk][0] : pk[2 * kk + 1][0];
                    unsigned int X1 = hfb ? pk[2 * kk][1] : pk[2 * kk + 1][1];
                    unsigned int O0 = hfb ? pk[2 * kk + 1][0] : pk[2 * kk][0];
                    unsigned int O1 = hfb ? pk[2 * kk + 1][1] : pk[2 * kk][1];
                    unsigned int Y0 = (unsigned int)__shfl_xor((int)X0, 32, 64);
                    unsigned int Y1 = (unsigned int)__shfl_xor((int)X1, 32, 64);
                    f3[j][nt * 2 + kk].u32[0] = hfb ? Y0 : O0;
                    f3[j][nt * 2 + kk].u32[1] = hfb ? Y1 : O1;
                    f3[j][nt * 2 + kk].u32[2] = hfb ? O0 : Y0;
                    f3[j][nt * 2 + kk].u32[3] = hfb ? O1 : Y1;
                }
            } else {
                f32x2 lo = {acc[j][0], acc[j][1]};
                f32x2 hi = {acc[j][2], acc[j][3]};
                lo = __builtin_elementwise_max(lo, zero2);
                hi = __builtin_elementwise_max(hi, zero2);
                unsigned int p0 = hpk(lo[0], lo[1]);
                unsigned int p1 = hpk(hi[0], hi[1]);
                f3[j][6].u32[0] = hfb ? 0u : p0;
                f3[j][6].u32[1] = hfb ? 0u : p1;
                f3[j][6].u32[2] = hfb ? 0u : 0x00003C00u;   // f16 1.0 (bias slot)
                f3[j][6].u32[3] = 0u;
            }
        }
    }

    // layer 3: dual accumulators; shared W2 + w3 loads; fold w3
    f32x2 oacc2[2] = {{0.f, 0.f}, {0.f, 0.f}};
    #pragma unroll
    for (int nt2 = 0; nt2 < 4; ++nt2) {
        f32x16 acc2[2];
        #pragma unroll
        for (int r = 0; r < 16; ++r) { acc2[0][r] = 0.f; acc2[1][r] = 0.f; }
        #pragma unroll
        for (int ks = 0; ks < 7; ++ks) {
            f16x8 wA = *(const f16x8*)&W2s[wrow[nt2] + ks * 16 + zoff];
            acc2[0] = __builtin_amdgcn_mfma_f32_32x32x16_f16(wA, f3[0][ks].v, acc2[0], 0, 0, 0);
            acc2[1] = __builtin_amdgcn_mfma_f32_32x32x16_f16(wA, f3[1][ks].v, acc2[1], 0, 0, 0);
        }
        uint4 wa = *(const uint4*)&w3p_s[hf * 32 + nt2 * 8 + zoff];
        uint4 wb2 = *(const uint4*)&w3p_s[hf * 32 + nt2 * 8 + 4 + zoff];
        unsigned int w8[8] = {wa.x, wa.y, wa.z, wa.w, wb2.x, wb2.y, wb2.z, wb2.w};
        f32x2 w3v[8];
        #pragma unroll
        for (int q = 0; q < 8; ++q) {
            w3v[q][0] = __uint_as_float(w8[q] << 16);
            w3v[q][1] = __uint_as_float(w8[q] & 0xFFFF0000u);
        }
        #pragma unroll
        for (int j = 0; j < 2; ++j)
            #pragma unroll
            for (int qi = 0; qi < 4; ++qi) {
                f32x2 lo = {acc2[j][4 * qi + 0], acc2[j][4 * qi + 1]};
                f32x2 hi = {acc2[j][4 * qi + 2], acc2[j][4 * qi + 3]};
                lo = __builtin_elementwise_max(lo, zero2);
                hi = __builtin_elementwise_max(hi, zero2);
                oacc2[j] = __builtin_elementwise_fma(lo, w3v[qi * 2], oacc2[j]);
                oacc2[j] = __builtin_elementwise_fma(hi, w3v[qi * 2 + 1], oacc2[j]);
            }
    }

    #pragma unroll
    for (int j = 0; j < 2; ++j) {
        float oacc = oacc2[j][0] + oacc2[j][1];
        float o = oacc + __shfl_xor(oacc, 32, 64) + b3;
        float dz = (o > 0.f) ? (o + 1.f) : expf(o);   // elu(o) + 1
        if (!hfb) tab[mr[j]] = dz;
    }
}

// eval_z: 64 samples/block, 4 threads/sample (point-strided), group shuffle
// reduce. z = sum_p ccw[p] * lerp(tab_k, x*xsc[p]); y = e1*0.5*x*z + o0.
__global__ __launch_bounds__(256)
void eval_z(const float* __restrict__ src0, float* __restrict__ dst0,
            const float* __restrict__ src1, float* __restrict__ dst1,
            const float* __restrict__ ws, const float* __restrict__ parts,
            float* __restrict__ partsOut, int np, int kbase, int n)
{
    __shared__ float tab_s[G];
    __shared__ float xsc_s[104], ccw_s[104];
    __shared__ float u0_s, inv_s, rmin_s[4], rmax_s[4];

    const int tid = threadIdx.x;
    const int lane = tid & 63;
    const int wv = tid >> 6;
    const int k = kbase + blockIdx.y;
    const float* __restrict__ src = blockIdx.y ? src1 : src0;
    float* __restrict__ dst = blockIdx.y ? dst1 : dst0;
    const bool doParts = (partsOut != 0) && (blockIdx.y == 0);

    const float* tg = ws + WS_TAB + k * G;
    for (int i = tid; i < G; i += 256) tab_s[i] = tg[i];
    if (tid < 104) {
        xsc_s[tid] = (tid < 101) ? ws[WS_XSC + tid] : 0.f;
        ccw_s[tid] = (tid < 101) ? ws[WS_CCW + tid] : 0.f;
    }
    if (tid < 64) {
        float pm = 1e30f, pM = -1e30f;
        for (int i = tid; i < np; i += 64) {
            pm = fminf(pm, parts[2 * i]);
            pM = fmaxf(pM, parts[2 * i + 1]);
        }
        #pragma unroll
        for (int off = 1; off < 64; off <<= 1) {
            pm = fminf(pm, __shfl_xor(pm, off, 64));
            pM = fmaxf(pM, __shfl_xor(pM, off, 64));
        }
        if (tid == 0) {
            float um = fminf(pm, 0.f), uM = fmaxf(pM, 0.f);
            float span = fmaxf(uM - um, 1e-5f);
            u0_s = um;
            inv_s = (float)(G - 1) / span;
        }
    }
    __syncthreads();

    const float u0 = u0_s, invd = inv_s;
    const int nn = blockIdx.x * SPB_E + (tid >> 2);
    const int psub = tid & 3;
    const float x = (nn < n) ? src[nn] : 0.f;
    float z = 0.f;
    for (int p = psub; p < 101; p += 4) {
        float u = x * xsc_s[p];
        float tt = fminf(fmaxf((u - u0) * invd, 0.f), (float)(G - 1) - 0.001f);
        int i = (int)tt;
        float f = tt - (float)i;
        float g0 = tab_s[i];
        float g1 = tab_s[i + 1];
        z = fmaf(ccw_s[p], fmaf(f, g1 - g0, g0), z);
    }
    // reduce across the 4-lane sample group
    z += __shfl_xor(z, 1, 64);
    z += __shfl_xor(z, 2, 64);

    const float e1 = ws[WS_EOH1 + k];
    const float o0 = ws[WS_OH0 + k];
    float y = fmaf(e1, 0.5f * x * z, o0);
    if (nn < n && psub == 0) dst[nn] = y;

    if (doParts) {
        float ymin = (nn < n) ? y : 1e30f;
        float ymax = (nn < n) ? y : -1e30f;
        #pragma unroll
        for (int off = 1; off < 64; off <<= 1) {
            ymin = fminf(ymin, __shfl_xor(ymin, off, 64));
            ymax = fmaxf(ymax, __shfl_xor(ymax, off, 64));
        }
        if (lane == 0) { rmin_s[wv] = ymin; rmax_s[wv] = ymax; }
        __syncthreads();
        if (tid == 0) {
            float m = fminf(fminf(rmin_s[0], rmin_s[1]), fminf(rmin_s[2], rmin_s[3]));
            float M = fmaxf(fmaxf(rmax_s[0], rmax_s[1]), fmaxf(rmax_s[2], rmax_s[3]));
            partsOut[2 * blockIdx.x] = m;
            partsOut[2 * blockIdx.x + 1] = M;
        }
    }
}

extern "C" void kernel_launch(void* const* d_in, const int* in_sizes, int n_in,
                              void* d_out, int out_size, void* d_ws, size_t ws_size,
                              hipStream_t stream)
{
    const float* logits = (const float*)d_in[0];
    const float* iW0 = (const float*)d_in[2];
    const float* ib0 = (const float*)d_in[3];
    const float* iW1 = (const float*)d_in[4];
    const float* ib1 = (const float*)d_in[5];
    const float* iW2 = (const float*)d_in[6];
    const float* ib2 = (const float*)d_in[7];
    const float* iW3 = (const float*)d_in[8];
    const float* ib3 = (const float*)d_in[9];
    const float* hb0 = (const float*)d_in[11];
    const float* hW1 = (const float*)d_in[12];
    const float* hb1 = (const float*)d_in[13];
    const float* hW2 = (const float*)d_in[14];
    const float* hb2 = (const float*)d_in[15];
    const float* hW3 = (const float*)d_in[16];
    const float* hb3 = (const float*)d_in[17];
    float* out = (float*)d_out;
    float* ws = (float*)d_ws;
    int n = in_sizes[0];
    int nbE = (n + SPB_E - 1) / SPB_E;     // 256 blocks at N=16384

    // 1) consts + logits passthrough + logits min/max partials (64 pairs)
    hipLaunchKernelGGL(prep_kernel, dim3(64), dim3(256), 0, stream,
                       logits, hb0, hW1, hb1, hW2, hb2, hW3, hb3, ws, out + 2 * n, n);
    // 2) tables for nets 0,1 over the logits-derived u-range
    hipLaunchKernelGGL(build_tab, dim3(G / 256, 2), dim3(256), 0, stream,
                       iW0, ib0, iW1, ib1, iW2, ib2, iW3, ib3, ws, ws + WS_P01, 64, 0);
    // 3) eval k=0 -> x2 (+ x2 min/max partials), k=1 -> y1
    hipLaunchKernelGGL(eval_z, dim3(nbE, 2), dim3(256), 0, stream,
                       logits, ws + WS_X2, logits, out,
                       ws, ws + WS_P01, ws + WS_P2, 64, 0, n);
    // 4) table for net 2 over the x2-derived u-range
    hipLaunchKernelGGL(build_tab, dim3(G / 256, 1), dim3(256), 0, stream,
                       iW0, ib0, iW1, ib1, iW2, ib2, iW3, ib3, ws, ws + WS_P2, nbE, 2);
    // 5) eval k=2 on x2 -> y2
    hipLaunchKernelGGL(eval_z, dim3(nbE, 1), dim3(256), 0, stream,
                       ws + WS_X2, out + n, ws + WS_X2, out + n,
                       ws, ws + WS_P2, (float*)0, nbE, 2, n);
}